// Round 5
// baseline (1714.135 us; speedup 1.0000x reference)
//
#include <hip/hip_runtime.h>
#include <hip/hip_bf16.h>

namespace {

constexpr int Sn = 2048;
constexpr int Dn = 128;
constexpr int BN = 32;           // k cols per tile
constexpr int THREADS = 256;     // 4 waves
constexpr int NT = Sn / BN;      // 64 tiles
constexpr long long OUT0 = 4LL * 16 * Sn * Dn;

constexpr int KSTR = 136;        // ushorts per K/Q LDS row (128 + 8 pad)
constexpr int VSTR = 34;         // ushorts per vt/w LDS row (32 + 2 pad)
constexpr int KT = BN * KSTR;    // 4352 ushorts
constexpr int VT = Dn * VSTR;    // 4352 ushorts
constexpr int WT = 64 * VSTR;    // 2176 ushorts

typedef short s16x4 __attribute__((ext_vector_type(4)));
typedef float f32x4 __attribute__((ext_vector_type(4)));

__device__ __forceinline__ unsigned short f2bu(float x) {
    return __bfloat16_as_ushort(__float2bfloat16(x));   // RNE
}
__device__ __forceinline__ unsigned pk2(float lo, float hi) {
    return (unsigned)f2bu(lo) | ((unsigned)f2bu(hi) << 16);
}

// ---- K-layout staging: 32x128 f32 -> bf16 rows, KSTR stride. Lane (sc,sr). ----
__device__ __forceinline__ void k_issue32(const float* __restrict__ g, int sc, int sr,
                                          float4* v) {
#pragma unroll
    for (int it = 0; it < 2; ++it) {
        const float4* gp = reinterpret_cast<const float4*>(
            g + (size_t)(sr + 16 * it) * Dn + sc * 8);
        v[2 * it]     = gp[0];
        v[2 * it + 1] = gp[1];
    }
}
__device__ __forceinline__ void k_write32(unsigned short* lds, int sc, int sr,
                                          const float4* v) {
#pragma unroll
    for (int it = 0; it < 2; ++it) {
        const int r = sr + 16 * it;
        uint4 u;
        u.x = pk2(v[2 * it].x,     v[2 * it].y);
        u.y = pk2(v[2 * it].z,     v[2 * it].w);
        u.z = pk2(v[2 * it + 1].x, v[2 * it + 1].y);
        u.w = pk2(v[2 * it + 1].z, v[2 * it + 1].w);
        *reinterpret_cast<uint4*>(reinterpret_cast<char*>(lds) + r * (KSTR * 2) + sc * 16) = u;
    }
}
// Q variant: scale folded in before bf16 rounding
__device__ __forceinline__ void q_write32(unsigned short* lds, int sc, int sr,
                                          const float4* v, float qs) {
#pragma unroll
    for (int it = 0; it < 2; ++it) {
        const int r = sr + 16 * it;
        uint4 u;
        u.x = pk2(v[2 * it].x * qs,     v[2 * it].y * qs);
        u.y = pk2(v[2 * it].z * qs,     v[2 * it].w * qs);
        u.z = pk2(v[2 * it + 1].x * qs, v[2 * it + 1].y * qs);
        u.w = pk2(v[2 * it + 1].z * qs, v[2 * it + 1].w * qs);
        *reinterpret_cast<uint4*>(reinterpret_cast<char*>(lds) + r * (KSTR * 2) + sc * 16) = u;
    }
}

// ---- V staging: 32x128 f32 -> vt[d][k] bf16, VSTR stride. Lane (tc,kp). ----
__device__ __forceinline__ void v_issue32(const float* __restrict__ g, int tc, int kp,
                                          float4* v) {
#pragma unroll
    for (int it = 0; it < 2; ++it) {
        const int kr = 2 * kp + 16 * it;
        v[2 * it]     = *reinterpret_cast<const float4*>(g + (size_t)kr * Dn + 4 * tc);
        v[2 * it + 1] = *reinterpret_cast<const float4*>(g + (size_t)(kr + 1) * Dn + 4 * tc);
    }
}
__device__ __forceinline__ void v_write32(unsigned short* vt, int tc, int kp,
                                          const float4* v) {
#pragma unroll
    for (int it = 0; it < 2; ++it) {
        const int kr = 2 * kp + 16 * it;
        const float a4[4] = {v[2 * it].x, v[2 * it].y, v[2 * it].z, v[2 * it].w};
        const float b4[4] = {v[2 * it + 1].x, v[2 * it + 1].y, v[2 * it + 1].z, v[2 * it + 1].w};
#pragma unroll
        for (int j = 0; j < 4; ++j) {
            const int d = 4 * tc + j;
            *reinterpret_cast<unsigned*>(reinterpret_cast<char*>(vt) + d * (VSTR * 2) + kr * 2)
                = pk2(a4[j], b4[j]);
        }
    }
}

#define MFMA16(A, B, C) __builtin_amdgcn_mfma_f32_16x16x16bf16_1k((A), (B), (C), 0, 0, 0)

// ---------------- pass A tile: rowsum accumulate, 1 barrier ----------------
#define PA_TILE(TO, KCUR, KNXT, MCUR, MNXT)                                          \
  {                                                                                  \
    const int to_ = (TO);                                                            \
    const bool pre_ = (to_ + 1 < NT);                                                \
    float4 kv_[4];                                                                   \
    if (pre_) {                                                                      \
      k_issue32(Kg + (size_t)(to_ + 1) * BN * Dn, sc, sr, kv_);                      \
      _Pragma("unroll") for (int r = 0; r < 4; ++r) {                                \
        MNXT[2 * r]     = mrow[r][(to_ + 1) * BN];                                   \
        MNXT[2 * r + 1] = mrow[r][(to_ + 1) * BN + 16];                              \
      }                                                                              \
    }                                                                                \
    f32x4 s0_ = zero, s1_ = zero;                                                    \
    __builtin_amdgcn_s_setprio(1);                                                   \
    _Pragma("unroll") for (int dsv = 0; dsv < 8; ++dsv) {                            \
      const int koff_ = dsv * 32 + lg * 8;                                           \
      const s16x4 b0_ = *reinterpret_cast<const s16x4*>(                             \
          reinterpret_cast<const char*>(KCUR) + lr * (KSTR * 2) + koff_);            \
      const s16x4 b1_ = *reinterpret_cast<const s16x4*>(                             \
          reinterpret_cast<const char*>(KCUR) + (16 + lr) * (KSTR * 2) + koff_);     \
      s0_ = MFMA16(qf[dsv], b0_, s0_);                                               \
      s1_ = MFMA16(qf[dsv], b1_, s1_);                                               \
    }                                                                                \
    __builtin_amdgcn_s_setprio(0);                                                   \
    _Pragma("unroll") for (int r = 0; r < 4; ++r) {                                  \
      const float e0_ = __builtin_amdgcn_exp2f(s0_[r]);                              \
      const float e1_ = __builtin_amdgcn_exp2f(s1_[r]);                              \
      rs[r] += (MCUR[2 * r]     ? e0_ : 0.f);                                        \
      rs[r] += (MCUR[2 * r + 1] ? e1_ : 0.f);                                        \
    }                                                                                \
    if (pre_) k_write32(KNXT, sc, sr, kv_);                                          \
    __syncthreads();                                                                 \
  }

// ---------------- pass B tile: weights + PV, 1 barrier ----------------
#define PB_TILE(TO, KCUR, KNXT, VCUR, VNXT, MCUR, MNXT)                              \
  {                                                                                  \
    const int to_ = (TO);                                                            \
    const int kc_ = to_ * BN;                                                        \
    const bool pre_ = (to_ + 1 < NT);                                                \
    float4 kv_[4], vv_[4];                                                           \
    if (pre_) {                                                                      \
      k_issue32(Kg + (size_t)(to_ + 1) * BN * Dn, sc, sr, kv_);                      \
      v_issue32(Vg + (size_t)(to_ + 1) * BN * Dn, tc, kp, vv_);                      \
      _Pragma("unroll") for (int r = 0; r < 4; ++r) {                                \
        MNXT[2 * r]     = mrow[r][(to_ + 1) * BN];                                   \
        MNXT[2 * r + 1] = mrow[r][(to_ + 1) * BN + 16];                              \
      }                                                                              \
    }                                                                                \
    f32x4 s0_ = zero, s1_ = zero;                                                    \
    __builtin_amdgcn_s_setprio(1);                                                   \
    _Pragma("unroll") for (int dsv = 0; dsv < 8; ++dsv) {                            \
      const int koff_ = dsv * 32 + lg * 8;                                           \
      const s16x4 b0_ = *reinterpret_cast<const s16x4*>(                             \
          reinterpret_cast<const char*>(KCUR) + lr * (KSTR * 2) + koff_);            \
      const s16x4 b1_ = *reinterpret_cast<const s16x4*>(                             \
          reinterpret_cast<const char*>(KCUR) + (16 + lr) * (KSTR * 2) + koff_);     \
      s0_ = MFMA16(qf[dsv], b0_, s0_);                                               \
      s1_ = MFMA16(qf[dsv], b1_, s1_);                                               \
    }                                                                                \
    __builtin_amdgcn_s_setprio(0);                                                   \
    float w0_[4], w1_[4];                                                            \
    _Pragma("unroll") for (int r = 0; r < 4; ++r) {                                  \
      const float e0_ = __builtin_amdgcn_exp2f(s0_[r] + li[r]);                      \
      const float e1_ = __builtin_amdgcn_exp2f(s1_[r] + li[r]);                      \
      w0_[r] = MCUR[2 * r]     ? e0_ : 0.f;                                          \
      w1_[r] = MCUR[2 * r + 1] ? e1_ : 0.f;                                          \
      unsigned short* wp_ = reinterpret_cast<unsigned short*>(                       \
          reinterpret_cast<char*>(wl) + (qrow + r) * (VSTR * 2));                    \
      wp_[lr]      = f2bu(w0_[r]);                                                   \
      wp_[16 + lr] = f2bu(w1_[r]);                                                   \
    }                                                                                \
    _Pragma("unroll") for (int kk = 0; kk < 2; ++kk) {                               \
      const int koff_ = kk * 32 + lg * 8;                                            \
      const s16x4 aw_ = *reinterpret_cast<const s16x4*>(                             \
          reinterpret_cast<const char*>(wl) + (16 * wv + lr) * (VSTR * 2) + koff_);  \
      __builtin_amdgcn_s_setprio(1);                                                 \
      _Pragma("unroll") for (int f = 0; f < 8; ++f) {                                \
        const s16x4 bv_ = *reinterpret_cast<const s16x4*>(                           \
            reinterpret_cast<const char*>(VCUR) + (16 * f + lr) * (VSTR * 2) + koff_);\
        oacc[f] = MFMA16(aw_, bv_, oacc[f]);                                         \
      }                                                                              \
      __builtin_amdgcn_s_setprio(0);                                                 \
    }                                                                                \
    _Pragma("unroll") for (int r = 0; r < 4; ++r) {                                  \
      float* wp_ = Wg + (size_t)(qrow + r) * Sn + kc_;                               \
      wp_[lr]      = w0_[r];                                                         \
      wp_[16 + lr] = w1_[r];                                                         \
    }                                                                                \
    if (pre_) {                                                                      \
      k_write32(KNXT, sc, sr, kv_);                                                  \
      v_write32(VNXT, tc, kp, vv_);                                                  \
    }                                                                                \
    __syncthreads();                                                                 \
  }

__global__ __launch_bounds__(THREADS, 3)
void attn_fused(const float* __restrict__ Q, const float* __restrict__ K,
                const float* __restrict__ V, const int* __restrict__ M,
                float* __restrict__ out) {
    __shared__ __align__(16) unsigned short smem[2 * KT + 2 * VT + WT];
    unsigned short* kb0 = smem;
    unsigned short* kb1 = smem + KT;
    unsigned short* vb0 = smem + 2 * KT;          // pass A: Q lo half | pass B: V^T dbuf
    unsigned short* vb1 = smem + 2 * KT + VT;     // pass A: Q hi half | pass B: V^T dbuf
    unsigned short* wl  = smem + 2 * KT + 2 * VT;

    const int tid  = threadIdx.x;
    const int lane = tid & 63;
    const int wv   = tid >> 6;
    const int lr   = lane & 15;
    const int lg   = lane >> 4;

    // XCD swizzle: 32 consecutive blocks per XCD share one head (K/V -> L2);
    // all heads on an XCD share one batch's mask.
    const int wg = blockIdx.x;           // 0..2047
    const int x  = wg & 7;               // XCD
    const int j  = wg >> 3;              // 0..255
    const int qt = j & 31;               // fast: q tile
    const int bh = 8 * x + (j >> 5);     // head
    const int b  = bh >> 4;              // H = 16
    const int qbase = qt * 64;

    const float* Qg = Q + ((size_t)bh * Sn + qbase) * Dn;
    const float* Kg = K + (size_t)bh * Sn * Dn;
    const float* Vg = V + (size_t)bh * Sn * Dn;
    const int*   Mg = M + ((size_t)b * Sn + qbase) * Sn;
    float*       Og = out + ((size_t)bh * Sn + qbase) * Dn;
    float*       Wg = out + OUT0 + ((size_t)bh * Sn + qbase) * Sn;

    const float QS = 1.4426950408889634f / 11.313708498984761f; // log2(e)/sqrt(D)
    const int qrow = 16 * wv + 4 * lg;

    const int sc = tid & 15, sr = tid >> 4;
    const int tc = tid & 31, kp = tid >> 5;

    const int* mrow[4];
#pragma unroll
    for (int r = 0; r < 4; ++r) mrow[r] = Mg + (size_t)(qrow + r) * Sn + lr;

    int mA[8], mB[8];
    const f32x4 zero = {0.f, 0.f, 0.f, 0.f};

    // ---------- prologue: K0 -> kb0; Q (scaled) -> vb0/vb1; mask tile0 ----------
    {
        float4 kv[4], q0[4], q1[4];
        k_issue32(Kg, sc, sr, kv);
        k_issue32(Qg, sc, sr, q0);
        k_issue32(Qg + 32 * Dn, sc, sr, q1);
#pragma unroll
        for (int r = 0; r < 4; ++r) {
            mA[2 * r]     = mrow[r][0];
            mA[2 * r + 1] = mrow[r][16];
        }
        k_write32(kb0, sc, sr, kv);
        q_write32(vb0, sc, sr, q0, QS);
        q_write32(vb1, sc, sr, q1, QS);
    }
    __syncthreads();

    s16x4 qf[8];
    {
        const unsigned short* qsrc = (wv >= 2) ? vb1 : vb0;
        const int qr = 16 * (wv & 1) + lr;
#pragma unroll
        for (int dsv = 0; dsv < 8; ++dsv)
            qf[dsv] = *reinterpret_cast<const s16x4*>(
                reinterpret_cast<const char*>(qsrc) + qr * (KSTR * 2) + dsv * 32 + lg * 8);
    }
    // no barrier needed: vb0/vb1 are not written again until pass B prologue,
    // which every wave reaches only after all NT pass-A barriers.

    // ---------------- pass A ----------------
    float rs[4] = {0.f, 0.f, 0.f, 0.f};
    for (int tt = 0; tt < NT; tt += 2) {
        PA_TILE(tt,     kb0, kb1, mA, mB)
        PA_TILE(tt + 1, kb1, kb0, mB, mA)
    }

    float li[4];
#pragma unroll
    for (int r = 0; r < 4; ++r) {
        float v = rs[r];
        v += __shfl_xor(v, 1);
        v += __shfl_xor(v, 2);
        v += __shfl_xor(v, 4);
        v += __shfl_xor(v, 8);
        li[r] = -__log2f(v);          // w = exp2(s + li) = exp(logit/scale)/rowsum
    }

    // ---------------- pass B prologue ----------------
    {
        float4 kv[4], vv[4];
        k_issue32(Kg, sc, sr, kv);
        v_issue32(Vg, tc, kp, vv);
#pragma unroll
        for (int r = 0; r < 4; ++r) {
            mA[2 * r]     = mrow[r][0];
            mA[2 * r + 1] = mrow[r][16];
        }
        k_write32(kb0, sc, sr, kv);
        v_write32(vb0, tc, kp, vv);
    }
    __syncthreads();

    // ---------------- pass B ----------------
    f32x4 oacc[8];
#pragma unroll
    for (int f = 0; f < 8; ++f) oacc[f] = zero;

    for (int tt = 0; tt < NT; tt += 2) {
        PB_TILE(tt,     kb0, kb1, vb0, vb1, mA, mB)
        PB_TILE(tt + 1, kb1, kb0, vb1, vb0, mB, mA)
    }

    // ---------------- epilogue: O ----------------
#pragma unroll
    for (int f = 0; f < 8; ++f)
#pragma unroll
        for (int r = 0; r < 4; ++r)
            Og[(size_t)(qrow + r) * Dn + 16 * f + lr] = oacc[f][r];
}

} // namespace

extern "C" void kernel_launch(void* const* d_in, const int* in_sizes, int n_in,
                              void* d_out, int out_size, void* d_ws, size_t ws_size,
                              hipStream_t stream) {
    (void)in_sizes; (void)n_in; (void)d_ws; (void)ws_size; (void)out_size;
    const float* Q = (const float*)d_in[0];
    const float* K = (const float*)d_in[1];
    const float* V = (const float*)d_in[2];
    const int*   M = (const int*)d_in[3];
    float* out = (float*)d_out;
    attn_fused<<<dim3(2048), dim3(THREADS), 0, stream>>>(Q, K, V, M, out);
}

// Round 6
// 1404.332 us; speedup vs baseline: 1.2206x; 1.2206x over previous
//
#include <hip/hip_runtime.h>
#include <hip/hip_bf16.h>

namespace {

constexpr int Sn = 2048;
constexpr int Dn = 128;
constexpr int BM = 128;          // q rows per workgroup
constexpr int BN = 64;           // k cols per tile
constexpr int THREADS = 512;     // 8 waves
constexpr int NT = Sn / BN;      // 32 tiles
constexpr long long OUT0 = 4LL * 16 * Sn * Dn;

constexpr int KSTR = 136;        // ushorts per K/Q LDS row (128 + 8 pad, 68 dwords)
constexpr int VSTR = 70;         // ushorts per vt/wl row (64 + 6 pad, 35 dwords: odd)
constexpr int KT = BN * KSTR;    // 8704 ushorts
constexpr int VT = Dn * VSTR;    // 8960 ushorts
constexpr int WT = BM * VSTR;    // 8960 ushorts

typedef short s16x4 __attribute__((ext_vector_type(4)));
typedef float f32x4 __attribute__((ext_vector_type(4)));

__device__ __forceinline__ unsigned short f2bu(float x) {
    return __bfloat16_as_ushort(__float2bfloat16(x));   // RNE
}
__device__ __forceinline__ unsigned pk2(float lo, float hi) {
    return (unsigned)f2bu(lo) | ((unsigned)f2bu(hi) << 16);
}

// ---- K-layout staging: 64x128 f32 -> bf16 rows (KSTR). 512 thr: sc=tid&15, sr=tid>>4. ----
__device__ __forceinline__ void k_issue64(const float* __restrict__ g, int sc, int sr,
                                          float4* v) {
#pragma unroll
    for (int it = 0; it < 2; ++it) {
        const float4* gp = reinterpret_cast<const float4*>(
            g + (size_t)(sr + 32 * it) * Dn + sc * 8);
        v[2 * it]     = gp[0];
        v[2 * it + 1] = gp[1];
    }
}
__device__ __forceinline__ void k_write64(unsigned short* lds, int sc, int sr,
                                          const float4* v) {
#pragma unroll
    for (int it = 0; it < 2; ++it) {
        const int r = sr + 32 * it;
        uint4 u;
        u.x = pk2(v[2 * it].x,     v[2 * it].y);
        u.y = pk2(v[2 * it].z,     v[2 * it].w);
        u.z = pk2(v[2 * it + 1].x, v[2 * it + 1].y);
        u.w = pk2(v[2 * it + 1].z, v[2 * it + 1].w);
        *reinterpret_cast<uint4*>(reinterpret_cast<char*>(lds) + r * (KSTR * 2) + sc * 16) = u;
    }
}
__device__ __forceinline__ void q_write64(unsigned short* lds, int sc, int sr,
                                          const float4* v, float qs) {
#pragma unroll
    for (int it = 0; it < 2; ++it) {
        const int r = sr + 32 * it;
        uint4 u;
        u.x = pk2(v[2 * it].x * qs,     v[2 * it].y * qs);
        u.y = pk2(v[2 * it].z * qs,     v[2 * it].w * qs);
        u.z = pk2(v[2 * it + 1].x * qs, v[2 * it + 1].y * qs);
        u.w = pk2(v[2 * it + 1].z * qs, v[2 * it + 1].w * qs);
        *reinterpret_cast<uint4*>(reinterpret_cast<char*>(lds) + r * (KSTR * 2) + sc * 16) = u;
    }
}

// ---- V staging: 64x128 f32 -> vt[d][k] bf16 (VSTR). 512 thr: tc=tid&31, kp=tid>>5. ----
__device__ __forceinline__ void v_issue64(const float* __restrict__ g, int tc, int kp,
                                          float4* v) {
#pragma unroll
    for (int it = 0; it < 2; ++it) {
        const int kr = 2 * kp + 32 * it;
        v[2 * it]     = *reinterpret_cast<const float4*>(g + (size_t)kr * Dn + 4 * tc);
        v[2 * it + 1] = *reinterpret_cast<const float4*>(g + (size_t)(kr + 1) * Dn + 4 * tc);
    }
}
__device__ __forceinline__ void v_write64(unsigned short* vt, int tc, int kp,
                                          const float4* v) {
#pragma unroll
    for (int it = 0; it < 2; ++it) {
        const int kr = 2 * kp + 32 * it;
        const float a4[4] = {v[2 * it].x, v[2 * it].y, v[2 * it].z, v[2 * it].w};
        const float b4[4] = {v[2 * it + 1].x, v[2 * it + 1].y, v[2 * it + 1].z, v[2 * it + 1].w};
#pragma unroll
        for (int j = 0; j < 4; ++j) {
            const int d = 4 * tc + j;
            *reinterpret_cast<unsigned*>(reinterpret_cast<char*>(vt) + d * (VSTR * 2) + kr * 2)
                = pk2(a4[j], b4[j]);
        }
    }
}

#define MFMA16(A, B, C) __builtin_amdgcn_mfma_f32_16x16x16bf16_1k((A), (B), (C), 0, 0, 0)

__global__ __launch_bounds__(THREADS, 4)
void attn_fused(const float* __restrict__ Q, const float* __restrict__ K,
                const float* __restrict__ V, const int* __restrict__ M,
                float* __restrict__ out) {
    // kbuf: K tile. vt: pass A = Q-hi stage / K double-buffer; pass B = V^T tile.
    __shared__ __align__(16) unsigned short smem[KT + VT + WT];
    unsigned short* kbuf = smem;
    unsigned short* vt   = smem + KT;
    unsigned short* wl   = smem + KT + VT;

    const int tid  = threadIdx.x;
    const int lane = tid & 63;
    const int wv   = tid >> 6;          // 0..7
    const int lr   = lane & 15;
    const int lg   = lane >> 4;

    const int bh    = blockIdx.y;
    const int b     = bh >> 4;          // H = 16
    const int qbase = blockIdx.x * BM;

    const float* Qg = Q + ((size_t)bh * Sn + qbase) * Dn;
    const float* Kg = K + (size_t)bh * Sn * Dn;
    const float* Vg = V + (size_t)bh * Sn * Dn;
    const int*   Mg = M + ((size_t)b * Sn + qbase) * Sn;
    float*       Og = out + ((size_t)bh * Sn + qbase) * Dn;
    float*       Wg = out + OUT0 + ((size_t)bh * Sn + qbase) * Sn;

    const float QS = 1.4426950408889634f / 11.313708498984761f; // log2(e)/sqrt(D)
    const int qrow = 16 * wv + 4 * lg;     // lane's S rows: qrow+r; cols 16t+lr

    const int sc = tid & 15, sr = tid >> 4;   // K staging map (sr 0..31)
    const int tc = tid & 31, kp = tid >> 5;   // V staging map (kp 0..15)

    const int* mrow[4];
#pragma unroll
    for (int r = 0; r < 4; ++r) mrow[r] = Mg + (size_t)(qrow + r) * Sn + lr;

    const f32x4 zero = {0.f, 0.f, 0.f, 0.f};

    // ---------- prologue: Q lo -> kbuf, Q hi -> vt (scaled); K0 issued early ----------
    float4 kv0[4];
    {
        float4 qlo[4], qhi[4];
        k_issue64(Qg, sc, sr, qlo);
        k_issue64(Qg + 64 * Dn, sc, sr, qhi);
        k_issue64(Kg, sc, sr, kv0);
        q_write64(kbuf, sc, sr, qlo, QS);
        q_write64(vt,   sc, sr, qhi, QS);
    }
    __syncthreads();

    s16x4 qf[8];
    {
        const unsigned short* qsrc = (wv >= 4) ? vt : kbuf;
        const int qr = 16 * (wv & 3) + lr;
#pragma unroll
        for (int dsv = 0; dsv < 8; ++dsv)
            qf[dsv] = *reinterpret_cast<const s16x4*>(
                reinterpret_cast<const char*>(qsrc) + qr * (KSTR * 2) + dsv * 32 + lg * 8);
    }
    __syncthreads();            // all qf reads done before kbuf overwritten
    k_write64(kbuf, sc, sr, kv0);
    __syncthreads();

    // ---------------- pass A: row sums of exp (K double-buffered, 1 barrier/tile) ----------------
    float rs[4] = {0.f, 0.f, 0.f, 0.f};
    {
        unsigned short* kcur = kbuf;
        unsigned short* knxt = vt;
        for (int t = 0; t < NT; ++t) {
            const bool pre = (t + 1 < NT);
            float4 kv[4];
            if (pre) k_issue64(Kg + (size_t)(t + 1) * BN * Dn, sc, sr, kv);

            int mv[16];
            const int kc = t * BN;
#pragma unroll
            for (int tt = 0; tt < 4; ++tt)
#pragma unroll
                for (int r = 0; r < 4; ++r) mv[4 * tt + r] = mrow[r][kc + 16 * tt];

            f32x4 s[4] = {zero, zero, zero, zero};
#pragma unroll
            for (int dsv = 0; dsv < 8; ++dsv) {
                const int koff = dsv * 32 + lg * 8;
#pragma unroll
                for (int tt = 0; tt < 4; ++tt) {
                    const s16x4 bb = *reinterpret_cast<const s16x4*>(
                        reinterpret_cast<const char*>(kcur) + (16 * tt + lr) * (KSTR * 2) + koff);
                    s[tt] = MFMA16(qf[dsv], bb, s[tt]);
                }
            }
#pragma unroll
            for (int tt = 0; tt < 4; ++tt)
#pragma unroll
                for (int r = 0; r < 4; ++r)
                    rs[r] += mv[4 * tt + r] ? __builtin_amdgcn_exp2f(s[tt][r]) : 0.f;

            if (pre) k_write64(knxt, sc, sr, kv);
            __syncthreads();
            unsigned short* tmp = kcur; kcur = knxt; knxt = tmp;
        }
    }

    // butterfly over lr bits: full 16-lane sum lands in every lane
    float li[4];
#pragma unroll
    for (int r = 0; r < 4; ++r) {
        float v = rs[r];
        v += __shfl_xor(v, 1);
        v += __shfl_xor(v, 2);
        v += __shfl_xor(v, 4);
        v += __shfl_xor(v, 8);
        li[r] = -__log2f(v);     // w = exp2(s + li) = exp(logit/scale)/rowsum
    }

    // ---------------- pass B prologue: K0 -> kbuf, V0^T -> vt ----------------
    {
        float4 kv[4], vv[4];
        k_issue64(Kg, sc, sr, kv);
        v_issue64(Vg, tc, kp, vv);
        k_write64(kbuf, sc, sr, kv);
        v_write64(vt, tc, kp, vv);
    }
    __syncthreads();

    // ---------------- pass B: weights + PV (issue-early / write-late, 2 barriers) ----------------
    f32x4 oacc[8];
#pragma unroll
    for (int f = 0; f < 8; ++f) oacc[f] = zero;

    for (int t = 0; t < NT; ++t) {
        const int kc = t * BN;
        const bool pre = (t + 1 < NT);
        float4 kv[4], vv[4];
        if (pre) {
            k_issue64(Kg + (size_t)(t + 1) * BN * Dn, sc, sr, kv);
            v_issue64(Vg + (size_t)(t + 1) * BN * Dn, tc, kp, vv);
        }

        int mv[16];
#pragma unroll
        for (int tt = 0; tt < 4; ++tt)
#pragma unroll
            for (int r = 0; r < 4; ++r) mv[4 * tt + r] = mrow[r][kc + 16 * tt];

        f32x4 s[4] = {zero, zero, zero, zero};
#pragma unroll
        for (int dsv = 0; dsv < 8; ++dsv) {
            const int koff = dsv * 32 + lg * 8;
#pragma unroll
            for (int tt = 0; tt < 4; ++tt) {
                const s16x4 bb = *reinterpret_cast<const s16x4*>(
                    reinterpret_cast<const char*>(kbuf) + (16 * tt + lr) * (KSTR * 2) + koff);
                s[tt] = MFMA16(qf[dsv], bb, s[tt]);
            }
        }

#pragma unroll
        for (int tt = 0; tt < 4; ++tt) {
#pragma unroll
            for (int r = 0; r < 4; ++r) {
                const float e = mv[4 * tt + r]
                    ? __builtin_amdgcn_exp2f(s[tt][r] + li[r]) : 0.f;
                Wg[(size_t)(qrow + r) * Sn + kc + 16 * tt + lr] = e;
                reinterpret_cast<unsigned short*>(
                    reinterpret_cast<char*>(wl) + (qrow + r) * (VSTR * 2))[16 * tt + lr] = f2bu(e);
            }
        }
        // no barrier: each wave writes/reads only its own 16 wl rows

#pragma unroll
        for (int kk = 0; kk < 4; ++kk) {
            const int koff = kk * 32 + lg * 8;
            const s16x4 aw = *reinterpret_cast<const s16x4*>(
                reinterpret_cast<const char*>(wl) + (16 * wv + lr) * (VSTR * 2) + koff);
#pragma unroll
            for (int f = 0; f < 8; ++f) {
                const s16x4 bv = *reinterpret_cast<const s16x4*>(
                    reinterpret_cast<const char*>(vt) + (16 * f + lr) * (VSTR * 2) + koff);
                oacc[f] = MFMA16(aw, bv, oacc[f]);
            }
        }

        __syncthreads();          // all waves done reading kbuf/vt tile t
        if (pre) {
            k_write64(kbuf, sc, sr, kv);
            v_write64(vt, tc, kp, vv);
        }
        __syncthreads();          // tile t+1 visible
    }

    // ---------------- epilogue: O ----------------
#pragma unroll
    for (int f = 0; f < 8; ++f)
#pragma unroll
        for (int r = 0; r < 4; ++r)
            Og[(size_t)(qrow + r) * Dn + 16 * f + lr] = oacc[f][r];
}

} // namespace

extern "C" void kernel_launch(void* const* d_in, const int* in_sizes, int n_in,
                              void* d_out, int out_size, void* d_ws, size_t ws_size,
                              hipStream_t stream) {
    (void)in_sizes; (void)n_in; (void)d_ws; (void)ws_size; (void)out_size;
    const float* Q = (const float*)d_in[0];
    const float* K = (const float*)d_in[1];
    const float* V = (const float*)d_in[2];
    const int*   M = (const int*)d_in[3];
    float* out = (float*)d_out;
    dim3 grid(Sn / BM, 4 * 16);   // (16 q tiles, B*H = 64)
    attn_fused<<<grid, dim3(THREADS), 0, stream>>>(Q, K, V, M, out);
}

// Round 7
// 840.776 us; speedup vs baseline: 2.0388x; 1.6703x over previous
//
#include <hip/hip_runtime.h>
#include <hip/hip_bf16.h>

namespace {

constexpr int Sn = 2048;
constexpr int Dn = 128;
constexpr int BN = 64;           // k cols per tile
constexpr int THREADS = 256;     // 4 waves
constexpr int NT = Sn / BN;      // 32 tiles
constexpr int NH = 64;           // B*H
constexpr long long OUT0 = 4LL * 16 * Sn * Dn;
constexpr float QSs = 1.4426950408889634f / 11.313708498984761f; // log2(e)/sqrt(D)

// d_ws layout (bytes)
constexpr size_t HB     = (size_t)Sn * Dn * 2;   // 512 KB per head (bf16)
constexpr size_t QB_OFF = 0;
constexpr size_t KB_OFF = HB * NH;               // 33,554,432
constexpr size_t VT_OFF = 2 * HB * NH;
constexpr size_t MB_OFF = 3 * HB * NH;           // 100,663,296
constexpr size_t WS_NEED = MB_OFF + (size_t)4 * Sn * 64 * 4;  // +2 MB mask bits

typedef short s16x4 __attribute__((ext_vector_type(4)));
typedef float f32x4 __attribute__((ext_vector_type(4)));

__device__ __forceinline__ unsigned short f2bu(float x) {
    return __bfloat16_as_ushort(__float2bfloat16(x));   // RNE
}
__device__ __forceinline__ unsigned pk2(float lo, float hi) {
    return (unsigned)f2bu(lo) | ((unsigned)f2bu(hi) << 16);
}

// async global->LDS, 16B per lane. LDS dest = wave-uniform base + lane*16 (HW).
// AS3 pointer value = low 32 bits of the generic LDS address.
__device__ __forceinline__ void glds16(const char* g, char* l) {
    __builtin_amdgcn_global_load_lds(
        (__attribute__((address_space(1))) void*)(uintptr_t)g,
        (__attribute__((address_space(3))) void*)(uintptr_t)(unsigned)(uintptr_t)l,
        16, 0, 0);
}

#define MFMA16(A, B, C) __builtin_amdgcn_mfma_f32_16x16x16bf16_1k((A), (B), (C), 0, 0, 0)

// ================= prepass kernels =================

// fp32 rows -> bf16 rows, 256B/row, XOR-swizzled within row: byte ^= (row&7)<<4
__global__ __launch_bounds__(256) void cvt_rows(const float* __restrict__ src,
                                                char* __restrict__ dst, float qs) {
    const int x = blockIdx.x * 256 + threadIdx.x;    // (row, chunk16B)
    const int c = x & 15;
    const int row = x >> 4;                          // bh*2048 + s; row&7 == s&7
    const float4* gp = reinterpret_cast<const float4*>(src + (size_t)row * Dn + c * 8);
    const float4 f0 = gp[0], f1 = gp[1];
    uint4 u;
    u.x = pk2(f0.x * qs, f0.y * qs);
    u.y = pk2(f0.z * qs, f0.w * qs);
    u.z = pk2(f1.x * qs, f1.y * qs);
    u.w = pk2(f1.z * qs, f1.w * qs);
    *reinterpret_cast<uint4*>(dst + (size_t)row * 256 + ((c * 16) ^ ((row & 7) << 4))) = u;
}

// V[bh][k][d] -> Vt tiled: per head, per tile t: [128 d-rows][64 k-cols] bf16 (16KB),
// row d stride 128B, swizzled byte ^= (d&7)<<4 within the 128B row.
__global__ __launch_bounds__(256) void cvt_vt(const float* __restrict__ V,
                                              char* __restrict__ vt) {
    const int x = blockIdx.x * 256 + threadIdx.x;
    const int d = x & 127;
    const int kc8 = (x >> 7) & 255;                  // chunk of 8 k values
    const int bh = x >> 15;
    const float* s = V + (size_t)bh * Sn * Dn + (size_t)kc8 * 8 * Dn + d;
    float f[8];
#pragma unroll
    for (int i = 0; i < 8; ++i) f[i] = s[(size_t)i * Dn];
    uint4 u;
    u.x = pk2(f[0], f[1]); u.y = pk2(f[2], f[3]);
    u.z = pk2(f[4], f[5]); u.w = pk2(f[6], f[7]);
    *reinterpret_cast<uint4*>(vt + (size_t)bh * HB + (size_t)(kc8 >> 3) * 16384
                              + d * 128 + (((kc8 & 7) * 16) ^ ((d & 7) << 4))) = u;
}

// mask int32 -> bitmask u32 per 32 cols
__global__ __launch_bounds__(256) void mask_pack(const int* __restrict__ M,
                                                 unsigned* __restrict__ mb) {
    const int x = blockIdx.x * 256 + threadIdx.x;    // (b,q,w): x = (b*2048+q)*64 + w
    const int w = x & 63;
    const int q = (x >> 6) & 2047;
    const int b = x >> 17;
    const int4* p = reinterpret_cast<const int4*>(M + ((size_t)b * Sn + q) * Sn + w * 32);
    unsigned u = 0;
#pragma unroll
    for (int i = 0; i < 8; ++i) {
        const int4 v = p[i];
        u |= (v.x != 0 ? 1u : 0u) << (4 * i);
        u |= (v.y != 0 ? 1u : 0u) << (4 * i + 1);
        u |= (v.z != 0 ? 1u : 0u) << (4 * i + 2);
        u |= (v.w != 0 ? 1u : 0u) << (4 * i + 3);
    }
    mb[x] = u;
}

// ================= main attention kernel =================

__global__ __launch_bounds__(THREADS, 2)
void attn_main(const char* __restrict__ ws, const unsigned* __restrict__ mbits,
               float* __restrict__ out) {
    __shared__ __align__(16) char smem[74496];
    char* kb0 = smem;                 // K tile dbuf (16KB each)
    char* kb1 = smem + 16384;
    char* vb0 = smem + 32768;         // V^T tile dbuf (16KB each)
    char* vb1 = smem + 49152;
    unsigned short* wl = reinterpret_cast<unsigned short*>(smem + 65536); // 64 x 70 ushorts

    const int tid  = threadIdx.x;
    const int lane = tid & 63;
    const int wv   = tid >> 6;
    const int lr   = lane & 15;
    const int lg   = lane >> 4;

    const int bh    = blockIdx.y;
    const int b     = bh >> 4;           // H = 16
    const int qbase = blockIdx.x * 64;

    const char* Qbh  = ws + (size_t)bh * HB;
    const char* Kbh  = ws + KB_OFF + (size_t)bh * HB;
    const char* Vtbh = ws + VT_OFF + (size_t)bh * HB;
    float*      Og   = out + ((size_t)bh * Sn + qbase) * Dn;
    float*      Wg   = out + OUT0 + ((size_t)bh * Sn + qbase) * Sn;

    const int qrow = 16 * wv + 4 * lg;   // lane's S rows: qrow+r; cols 16tt+lr

    const unsigned* mbase[4];
#pragma unroll
    for (int r = 0; r < 4; ++r)
        mbase[r] = mbits + ((size_t)b * Sn + qbase + qrow + r) * 64;

    // Q fragments straight from global (pre-scaled, pre-swizzled)
    s16x4 qf[8];
    {
        const char* qp = Qbh + (size_t)(qbase + 16 * wv + lr) * 256;
#pragma unroll
        for (int dsv = 0; dsv < 8; ++dsv)
            qf[dsv] = *reinterpret_cast<const s16x4*>(
                qp + ((dsv * 32 + lg * 8) ^ ((lr & 7) << 4)));
    }

    const f32x4 zero = {0.f, 0.f, 0.f, 0.f};

    auto dma = [&](const char* gtile, char* buf) {   // copy one 16KB tile async
        const char* g = gtile + wv * 4096 + lane * 16;
        char* l = buf + wv * 4096;                   // wave-uniform LDS base
#pragma unroll
        for (int i = 0; i < 4; ++i) glds16(g + i * 1024, l + i * 1024);
    };

    // ---------------- pass A: row sums of exp ----------------
    dma(Kbh, kb0);
    __syncthreads();

    float rs[4] = {0.f, 0.f, 0.f, 0.f};
    {
        char* kcur = kb0;
        char* knxt = kb1;
        for (int t = 0; t < NT; ++t) {
            if (t + 1 < NT) dma(Kbh + (size_t)(t + 1) * 16384, knxt);

            uint2 mw[4];
#pragma unroll
            for (int r = 0; r < 4; ++r)
                mw[r] = *reinterpret_cast<const uint2*>(mbase[r] + 2 * t);

            f32x4 s[4] = {zero, zero, zero, zero};
#pragma unroll
            for (int dsv = 0; dsv < 8; ++dsv) {
                const int koff = (dsv * 32 + lg * 8) ^ ((lr & 7) << 4);
#pragma unroll
                for (int tt = 0; tt < 4; ++tt) {
                    const s16x4 bb = *reinterpret_cast<const s16x4*>(
                        kcur + (16 * tt + lr) * 256 + koff);
                    s[tt] = MFMA16(qf[dsv], bb, s[tt]);
                }
            }
#pragma unroll
            for (int tt = 0; tt < 4; ++tt) {
#pragma unroll
                for (int r = 0; r < 4; ++r) {
                    const unsigned wsel = (tt < 2) ? mw[r].x : mw[r].y;
                    const unsigned bit = (wsel >> ((tt & 1) * 16 + lr)) & 1u;
                    rs[r] += bit ? __builtin_amdgcn_exp2f(s[tt][r]) : 0.f;
                }
            }
            __syncthreads();   // emitted vmcnt(0) also completes the t+1 DMA
            char* tmp = kcur; kcur = knxt; knxt = tmp;
        }
    }

    // butterfly over lr bits: full 16-lane sum in every lane
    float li[4];
#pragma unroll
    for (int r = 0; r < 4; ++r) {
        float v = rs[r];
        v += __shfl_xor(v, 1);
        v += __shfl_xor(v, 2);
        v += __shfl_xor(v, 4);
        v += __shfl_xor(v, 8);
        li[r] = -__log2f(v);   // w = exp2(s + li)
    }

    // ---------------- pass B: weights + PV ----------------
    dma(Kbh, kb0);
    dma(Vtbh, vb0);
    __syncthreads();

    f32x4 oacc[8];
#pragma unroll
    for (int f = 0; f < 8; ++f) oacc[f] = zero;

    {
        char* kcur = kb0; char* knxt = kb1;
        char* vcur = vb0; char* vnxt = vb1;
        for (int t = 0; t < NT; ++t) {
            const int kc = t * BN;
            if (t + 1 < NT) {
                dma(Kbh  + (size_t)(t + 1) * 16384, knxt);
                dma(Vtbh + (size_t)(t + 1) * 16384, vnxt);
            }

            uint2 mw[4];
#pragma unroll
            for (int r = 0; r < 4; ++r)
                mw[r] = *reinterpret_cast<const uint2*>(mbase[r] + 2 * t);

            f32x4 s[4] = {zero, zero, zero, zero};
#pragma unroll
            for (int dsv = 0; dsv < 8; ++dsv) {
                const int koff = (dsv * 32 + lg * 8) ^ ((lr & 7) << 4);
#pragma unroll
                for (int tt = 0; tt < 4; ++tt) {
                    const s16x4 bb = *reinterpret_cast<const s16x4*>(
                        kcur + (16 * tt + lr) * 256 + koff);
                    s[tt] = MFMA16(qf[dsv], bb, s[tt]);
                }
            }

#pragma unroll
            for (int tt = 0; tt < 4; ++tt) {
#pragma unroll
                for (int r = 0; r < 4; ++r) {
                    const unsigned wsel = (tt < 2) ? mw[r].x : mw[r].y;
                    const unsigned bit = (wsel >> ((tt & 1) * 16 + lr)) & 1u;
                    const float e = bit ? __builtin_amdgcn_exp2f(s[tt][r] + li[r]) : 0.f;
                    Wg[(size_t)(qrow + r) * Sn + kc + 16 * tt + lr] = e;
                    wl[(qrow + r) * 70 + 16 * tt + lr] = f2bu(e);
                }
            }
            // no barrier: each wave writes/reads only its own 16 wl rows

#pragma unroll
            for (int kk = 0; kk < 4; ++kk) {
                const s16x4 aw = *reinterpret_cast<const s16x4*>(
                    reinterpret_cast<const char*>(wl) + (16 * wv + lr) * 140 + kk * 32 + lg * 8);
#pragma unroll
                for (int f = 0; f < 8; ++f) {
                    const s16x4 bv = *reinterpret_cast<const s16x4*>(
                        vcur + (16 * f + lr) * 128 + ((kk * 32 + lg * 8) ^ ((lr & 7) << 4)));
                    oacc[f] = MFMA16(aw, bv, oacc[f]);
                }
            }

            __syncthreads();
            char* tmp = kcur; kcur = knxt; knxt = tmp;
            tmp = vcur; vcur = vnxt; vnxt = tmp;
        }
    }

    // ---------------- epilogue: O ----------------
#pragma unroll
    for (int f = 0; f < 8; ++f)
#pragma unroll
        for (int r = 0; r < 4; ++r)
            Og[(size_t)(qrow + r) * Dn + 16 * f + lr] = oacc[f][r];
}

// ================= fallback (round-3 kernel, verified 1006 us) =================

constexpr int FQSTR = 136;
constexpr int FVSTR = 68;

__device__ __forceinline__ void fbk_issue(const float* __restrict__ g, int sc, int sr,
                                          float4* v) {
#pragma unroll
    for (int it = 0; it < 4; ++it) {
        const float4* gp = reinterpret_cast<const float4*>(
            g + (size_t)(sr + 16 * it) * Dn + sc * 8);
        v[2 * it]     = gp[0];
        v[2 * it + 1] = gp[1];
    }
}
__device__ __forceinline__ void fbk_write(unsigned short* lds, int sc, int sr,
                                          const float4* v) {
#pragma unroll
    for (int it = 0; it < 4; ++it) {
        const int r = sr + 16 * it;
        uint4 u;
        u.x = pk2(v[2 * it].x,     v[2 * it].y);
        u.y = pk2(v[2 * it].z,     v[2 * it].w);
        u.z = pk2(v[2 * it + 1].x, v[2 * it + 1].y);
        u.w = pk2(v[2 * it + 1].z, v[2 * it + 1].w);
        *reinterpret_cast<uint4*>(reinterpret_cast<char*>(lds) + r * (FQSTR * 2) + sc * 16) = u;
    }
}
__device__ __forceinline__ void fbv_issue(const float* __restrict__ g, int tc, int kp,
                                          float4* v) {
#pragma unroll
    for (int it = 0; it < 4; ++it) {
        const int kr = 2 * (kp + 8 * it);
        v[2 * it]     = *reinterpret_cast<const float4*>(g + (size_t)kr * Dn + 4 * tc);
        v[2 * it + 1] = *reinterpret_cast<const float4*>(g + (size_t)(kr + 1) * Dn + 4 * tc);
    }
}
__device__ __forceinline__ void fbv_write(unsigned short* vt, int tc, int kp,
                                          const float4* v) {
#pragma unroll
    for (int it = 0; it < 4; ++it) {
        const int kr = 2 * (kp + 8 * it);
        const float a4[4] = {v[2 * it].x, v[2 * it].y, v[2 * it].z, v[2 * it].w};
        const float b4[4] = {v[2 * it + 1].x, v[2 * it + 1].y, v[2 * it + 1].z, v[2 * it + 1].w};
#pragma unroll
        for (int j = 0; j < 4; ++j) {
            const int d = 4 * tc + j;
            *reinterpret_cast<unsigned*>(reinterpret_cast<char*>(vt) + d * (FVSTR * 2) + kr * 2)
                = pk2(a4[j], b4[j]);
        }
    }
}

__global__ __launch_bounds__(256)
void attn_fb(const float* __restrict__ Q, const float* __restrict__ K,
             const float* __restrict__ V, const int* __restrict__ M,
             float* __restrict__ out) {
    __shared__ __align__(16) unsigned short fsm[8704 * 2 + 64 * FVSTR];
    unsigned short* bufA = fsm;
    unsigned short* bufB = fsm + 8704;
    unsigned short* wl2  = fsm + 17408;

    const int tid  = threadIdx.x;
    const int lane = tid & 63;
    const int wv   = tid >> 6;
    const int lr   = lane & 15;
    const int lg   = lane >> 4;

    const int bh    = blockIdx.y;
    const int b     = bh >> 4;
    const int qbase = blockIdx.x * 64;

    const float* Qg = Q + ((size_t)bh * Sn + qbase) * Dn;
    const float* Kg = K + (size_t)bh * Sn * Dn;
    const float* Vg = V + (size_t)bh * Sn * Dn;
    const int*   Mg = M + ((size_t)b * Sn + qbase) * Sn;
    float*       Og = out + ((size_t)bh * Sn + qbase) * Dn;
    float*       Wg = out + OUT0 + ((size_t)bh * Sn + qbase) * Sn;

    const float scl2 = QSs;
    const int qrow = 16 * wv + 4 * lg;

    const int sc = tid & 15, sr = tid >> 4;
    const int tc = tid & 31, kp = tid >> 5;

    const int* mrow[4];
#pragma unroll
    for (int r = 0; r < 4; ++r) mrow[r] = Mg + (size_t)(qrow + r) * Sn + lr;

    {
        float4 qv[8], kv[8];
        fbk_issue(Qg, sc, sr, qv);
        fbk_issue(Kg, sc, sr, kv);
        fbk_write(bufB, sc, sr, qv);
        fbk_write(bufA, sc, sr, kv);
    }
    __syncthreads();
    s16x4 qf[8];
#pragma unroll
    for (int dsv = 0; dsv < 8; ++dsv)
        qf[dsv] = *reinterpret_cast<const s16x4*>(
            reinterpret_cast<const char*>(bufB) + (16 * wv + lr) * (FQSTR * 2) + dsv * 32 + lg * 8);
    __syncthreads();

    const f32x4 zero = {0.f, 0.f, 0.f, 0.f};

    auto qk_tile = [&](const unsigned short* kb) {
        struct { f32x4 t[4]; } s;
#pragma unroll
        for (int t = 0; t < 4; ++t) s.t[t] = zero;
#pragma unroll
        for (int dsv = 0; dsv < 8; ++dsv) {
            const int koff = dsv * 32 + lg * 8;
#pragma unroll
            for (int t = 0; t < 4; ++t) {
                const s16x4 bb = *reinterpret_cast<const s16x4*>(
                    reinterpret_cast<const char*>(kb) + (16 * t + lr) * (FQSTR * 2) + koff);
                s.t[t] = MFMA16(qf[dsv], bb, s.t[t]);
            }
        }
        return s;
    };

    float rs[4] = {0.f, 0.f, 0.f, 0.f};
    for (int t = 0; t < NT; ++t) {
        unsigned short* cur = (t & 1) ? bufB : bufA;
        unsigned short* nxt = (t & 1) ? bufA : bufB;
        float4 kv[8];
        const bool pre = (t + 1 < NT);
        if (pre) fbk_issue(Kg + (size_t)(t + 1) * BN * Dn, sc, sr, kv);

        int mv[16];
        const int kc = t * BN;
#pragma unroll
        for (int tt = 0; tt < 4; ++tt)
#pragma unroll
            for (int r = 0; r < 4; ++r) mv[4 * tt + r] = mrow[r][kc + 16 * tt];

        auto s = qk_tile(cur);
#pragma unroll
        for (int tt = 0; tt < 4; ++tt)
#pragma unroll
            for (int r = 0; r < 4; ++r)
                rs[r] += mv[4 * tt + r] ? __builtin_amdgcn_exp2f(s.t[tt][r] * scl2) : 0.f;

        if (pre) fbk_write(nxt, sc, sr, kv);
        __syncthreads();
    }

    float inv[4];
#pragma unroll
    for (int r = 0; r < 4; ++r) {
        float v = rs[r];
        v += __shfl_xor(v, 1);
        v += __shfl_xor(v, 2);
        v += __shfl_xor(v, 4);
        v += __shfl_xor(v, 8);
        inv[r] = 1.0f / v;
    }

    {
        float4 kv0[8], vv0[8];
        fbk_issue(Kg, sc, sr, kv0);
        fbv_issue(Vg, tc, kp, vv0);
        fbk_write(bufA, sc, sr, kv0);
        fbv_write(bufB, tc, kp, vv0);
    }
    __syncthreads();

    f32x4 oacc[8];
#pragma unroll
    for (int f = 0; f < 8; ++f) oacc[f] = zero;

    for (int t = 0; t < NT; ++t) {
        float4 kv[8], vv[8];
        const bool pre = (t + 1 < NT);
        if (pre) {
            fbk_issue(Kg + (size_t)(t + 1) * BN * Dn, sc, sr, kv);
            fbv_issue(Vg + (size_t)(t + 1) * BN * Dn, tc, kp, vv);
        }

        int mv[16];
        const int kc = t * BN;
#pragma unroll
        for (int tt = 0; tt < 4; ++tt)
#pragma unroll
            for (int r = 0; r < 4; ++r) mv[4 * tt + r] = mrow[r][kc + 16 * tt];

        auto s = qk_tile(bufA);

#pragma unroll
        for (int tt = 0; tt < 4; ++tt) {
#pragma unroll
            for (int r = 0; r < 4; ++r) {
                const float e = mv[4 * tt + r] ? __builtin_amdgcn_exp2f(s.t[tt][r] * scl2) : 0.f;
                const float w = e * inv[r];
                Wg[(size_t)(qrow + r) * Sn + kc + 16 * tt + lr] = w;
                reinterpret_cast<unsigned short*>(
                    reinterpret_cast<char*>(wl2) + (qrow + r) * (FVSTR * 2))[16 * tt + lr] = f2bu(w);
            }
        }

#pragma unroll
        for (int kk = 0; kk < 4; ++kk) {
            const int koff = kk * 32 + lg * 8;
            const s16x4 aw = *reinterpret_cast<const s16x4*>(
                reinterpret_cast<const char*>(wl2) + (16 * wv + lr) * (FVSTR * 2) + koff);
#pragma unroll
            for (int f = 0; f < 8; ++f) {
                const s16x4 bv = *reinterpret_cast<const s16x4*>(
                    reinterpret_cast<const char*>(bufB) + (16 * f + lr) * (FVSTR * 2) + koff);
                oacc[f] = MFMA16(aw, bv, oacc[f]);
            }
        }
        __syncthreads();
        if (pre) {
            fbk_write(bufA, sc, sr, kv);
            fbv_write(bufB, tc, kp, vv);
        }
        __syncthreads();
    }

#pragma unroll
    for (int f = 0; f < 8; ++f)
#pragma unroll
        for (int r = 0; r < 4; ++r)
            Og[(size_t)(qrow + r) * Dn + 16 * f + lr] = oacc[f][r];
}

} // namespace

extern "C" void kernel_launch(void* const* d_in, const int* in_sizes, int n_in,
                              void* d_out, int out_size, void* d_ws, size_t ws_size,
                              hipStream_t stream) {
    (void)in_sizes; (void)n_in; (void)out_size;
    const float* Q = (const float*)d_in[0];
    const float* K = (const float*)d_in[1];
    const float* V = (const float*)d_in[2];
    const int*   M = (const int*)d_in[3];
    float* out = (float*)d_out;

    if (ws_size >= WS_NEED) {
        char* ws = (char*)d_ws;
        cvt_rows<<<dim3(8192), dim3(256), 0, stream>>>(Q, ws + QB_OFF, QSs);
        cvt_rows<<<dim3(8192), dim3(256), 0, stream>>>(K, ws + KB_OFF, 1.0f);
        cvt_vt  <<<dim3(8192), dim3(256), 0, stream>>>(V, ws + VT_OFF);
        mask_pack<<<dim3(2048), dim3(256), 0, stream>>>(M, (unsigned*)(ws + MB_OFF));
        attn_main<<<dim3(Sn / 64, NH), dim3(THREADS), 0, stream>>>(
            ws, (const unsigned*)(ws + MB_OFF), out);
    } else {
        attn_fb<<<dim3(Sn / 64, NH), dim3(256), 0, stream>>>(Q, K, V, M, out);
    }
}

// Round 8
// 834.839 us; speedup vs baseline: 2.0533x; 1.0071x over previous
//
#include <hip/hip_runtime.h>
#include <hip/hip_bf16.h>

namespace {

constexpr int Sn = 2048;
constexpr int Dn = 128;
constexpr int BN = 64;           // k cols per tile
constexpr int THREADS = 256;     // 4 waves
constexpr int NT = Sn / BN;      // 32 tiles
constexpr int NH = 64;           // B*H
constexpr long long OUT0 = 4LL * 16 * Sn * Dn;
constexpr float QSs = 1.4426950408889634f / 11.313708498984761f; // log2(e)/sqrt(D)

// d_ws layout (bytes)
constexpr size_t HB     = (size_t)Sn * Dn * 2;   // 512 KB per head (bf16)
constexpr size_t QB_OFF = 0;
constexpr size_t KB_OFF = HB * NH;               // 33,554,432
constexpr size_t VT_OFF = 2 * HB * NH;
constexpr size_t MB_OFF = 3 * HB * NH;           // 100,663,296
constexpr size_t WS_NEED = MB_OFF + (size_t)4 * Sn * 64 * 4;  // +2 MB mask bits

typedef short s16x4 __attribute__((ext_vector_type(4)));
typedef float f32x4 __attribute__((ext_vector_type(4)));

__device__ __forceinline__ unsigned short f2bu(float x) {
    return __bfloat16_as_ushort(__float2bfloat16(x));   // RNE
}
__device__ __forceinline__ unsigned pk2(float lo, float hi) {
    return (unsigned)f2bu(lo) | ((unsigned)f2bu(hi) << 16);
}

// async global->LDS, 16B per lane. LDS dest = wave-uniform base + lane*16 (HW).
// AS3 pointer value = low 32 bits of the generic LDS address.
__device__ __forceinline__ void glds16(const char* g, char* l) {
    __builtin_amdgcn_global_load_lds(
        (__attribute__((address_space(1))) void*)(uintptr_t)g,
        (__attribute__((address_space(3))) void*)(uintptr_t)(unsigned)(uintptr_t)l,
        16, 0, 0);
}

#define MFMA16(A, B, C) __builtin_amdgcn_mfma_f32_16x16x16bf16_1k((A), (B), (C), 0, 0, 0)

// ================= prepass kernels =================

// fp32 rows -> bf16 rows, 256B/row, XOR-swizzled within row: byte ^= (row&7)<<4
__global__ __launch_bounds__(256) void cvt_rows(const float* __restrict__ src,
                                                char* __restrict__ dst, float qs) {
    const int x = blockIdx.x * 256 + threadIdx.x;    // (row, chunk16B)
    const int c = x & 15;
    const int row = x >> 4;                          // bh*2048 + s; row&7 == s&7
    const float4* gp = reinterpret_cast<const float4*>(src + (size_t)row * Dn + c * 8);
    const float4 f0 = gp[0], f1 = gp[1];
    uint4 u;
    u.x = pk2(f0.x * qs, f0.y * qs);
    u.y = pk2(f0.z * qs, f0.w * qs);
    u.z = pk2(f1.x * qs, f1.y * qs);
    u.w = pk2(f1.z * qs, f1.w * qs);
    *reinterpret_cast<uint4*>(dst + (size_t)row * 256 + ((c * 16) ^ ((row & 7) << 4))) = u;
}

// V[bh][k][d] -> Vt tiled: per head, per tile t: [128 d-rows][64 k-cols] bf16 (16KB),
// row d stride 128B, swizzled byte ^= (d&7)<<4 within the 128B row.
__global__ __launch_bounds__(256) void cvt_vt(const float* __restrict__ V,
                                              char* __restrict__ vt) {
    const int x = blockIdx.x * 256 + threadIdx.x;
    const int d = x & 127;
    const int kc8 = (x >> 7) & 255;                  // chunk of 8 k values
    const int bh = x >> 15;
    const float* s = V + (size_t)bh * Sn * Dn + (size_t)kc8 * 8 * Dn + d;
    float f[8];
#pragma unroll
    for (int i = 0; i < 8; ++i) f[i] = s[(size_t)i * Dn];
    uint4 u;
    u.x = pk2(f[0], f[1]); u.y = pk2(f[2], f[3]);
    u.z = pk2(f[4], f[5]); u.w = pk2(f[6], f[7]);
    *reinterpret_cast<uint4*>(vt + (size_t)bh * HB + (size_t)(kc8 >> 3) * 16384
                              + d * 128 + (((kc8 & 7) * 16) ^ ((d & 7) << 4))) = u;
}

// mask int32 -> bitmask u32 per 32 cols
__global__ __launch_bounds__(256) void mask_pack(const int* __restrict__ M,
                                                 unsigned* __restrict__ mb) {
    const int x = blockIdx.x * 256 + threadIdx.x;    // (b,q,w): x = (b*2048+q)*64 + w
    const int w = x & 63;
    const int q = (x >> 6) & 2047;
    const int b = x >> 17;
    const int4* p = reinterpret_cast<const int4*>(M + ((size_t)b * Sn + q) * Sn + w * 32);
    unsigned u = 0;
#pragma unroll
    for (int i = 0; i < 8; ++i) {
        const int4 v = p[i];
        u |= (v.x != 0 ? 1u : 0u) << (4 * i);
        u |= (v.y != 0 ? 1u : 0u) << (4 * i + 1);
        u |= (v.z != 0 ? 1u : 0u) << (4 * i + 2);
        u |= (v.w != 0 ? 1u : 0u) << (4 * i + 3);
    }
    mb[x] = u;
}

// ================= main attention kernel =================

__global__ __launch_bounds__(THREADS, 2)
void attn_main(const char* __restrict__ ws, const unsigned* __restrict__ mbits,
               float* __restrict__ out) {
    __shared__ __align__(16) char smem[74496];
    char* kb0 = smem;                 // K tile dbuf (16KB each)
    char* kb1 = smem + 16384;
    char* vb0 = smem + 32768;         // V^T tile dbuf (16KB each)
    char* vb1 = smem + 49152;
    unsigned short* wl = reinterpret_cast<unsigned short*>(smem + 65536); // 64 x 70 ushorts

    const int tid  = threadIdx.x;
    const int lane = tid & 63;
    const int wv   = tid >> 6;
    const int lr   = lane & 15;
    const int lg   = lane >> 4;

    const int bh    = blockIdx.y;
    const int b     = bh >> 4;           // H = 16
    const int qbase = blockIdx.x * 64;

    const char* Qbh  = ws + (size_t)bh * HB;
    const char* Kbh  = ws + KB_OFF + (size_t)bh * HB;
    const char* Vtbh = ws + VT_OFF + (size_t)bh * HB;
    float*      Og   = out + ((size_t)bh * Sn + qbase) * Dn;
    float*      Wg   = out + OUT0 + ((size_t)bh * Sn + qbase) * Sn;

    const int qrow = 16 * wv + 4 * lg;   // lane's S rows: qrow+r; cols 16tt+lr

    const unsigned* mbase[4];
#pragma unroll
    for (int r = 0; r < 4; ++r)
        mbase[r] = mbits + ((size_t)b * Sn + qbase + qrow + r) * 64;

    // Q fragments straight from global (pre-scaled, pre-swizzled)
    s16x4 qf[8];
    {
        const char* qp = Qbh + (size_t)(qbase + 16 * wv + lr) * 256;
#pragma unroll
        for (int dsv = 0; dsv < 8; ++dsv)
            qf[dsv] = *reinterpret_cast<const s16x4*>(
                qp + ((dsv * 32 + lg * 8) ^ ((lr & 7) << 4)));
    }

    const f32x4 zero = {0.f, 0.f, 0.f, 0.f};

    auto dma = [&](const char* gtile, char* buf) {   // copy one 16KB tile async
        const char* g = gtile + wv * 4096 + lane * 16;
        char* l = buf + wv * 4096;                   // wave-uniform LDS base
#pragma unroll
        for (int i = 0; i < 4; ++i) glds16(g + i * 1024, l + i * 1024);
    };

    // ---------------- pass A: row sums of exp ----------------
    dma(Kbh, kb0);
    __syncthreads();

    float rs[4] = {0.f, 0.f, 0.f, 0.f};
    {
        char* kcur = kb0;
        char* knxt = kb1;
        for (int t = 0; t < NT; ++t) {
            if (t + 1 < NT) dma(Kbh + (size_t)(t + 1) * 16384, knxt);

            uint2 mw[4];
#pragma unroll
            for (int r = 0; r < 4; ++r)
                mw[r] = *reinterpret_cast<const uint2*>(mbase[r] + 2 * t);

            f32x4 s[4] = {zero, zero, zero, zero};
#pragma unroll
            for (int dsv = 0; dsv < 8; ++dsv) {
                const int koff = (dsv * 32 + lg * 8) ^ ((lr & 7) << 4);
#pragma unroll
                for (int tt = 0; tt < 4; ++tt) {
                    const s16x4 bb = *reinterpret_cast<const s16x4*>(
                        kcur + (16 * tt + lr) * 256 + koff);
                    s[tt] = MFMA16(qf[dsv], bb, s[tt]);
                }
            }
#pragma unroll
            for (int tt = 0; tt < 4; ++tt) {
#pragma unroll
                for (int r = 0; r < 4; ++r) {
                    const unsigned wsel = (tt < 2) ? mw[r].x : mw[r].y;
                    const unsigned bit = (wsel >> ((tt & 1) * 16 + lr)) & 1u;
                    rs[r] += bit ? __builtin_amdgcn_exp2f(s[tt][r]) : 0.f;
                }
            }
            __syncthreads();   // emitted vmcnt(0) also completes the t+1 DMA
            char* tmp = kcur; kcur = knxt; knxt = tmp;
        }
    }

    // butterfly over lr bits: full 16-lane sum in every lane
    float li[4];
#pragma unroll
    for (int r = 0; r < 4; ++r) {
        float v = rs[r];
        v += __shfl_xor(v, 1);
        v += __shfl_xor(v, 2);
        v += __shfl_xor(v, 4);
        v += __shfl_xor(v, 8);
        li[r] = -__log2f(v);   // w = exp2(s + li)
    }

    // ---------------- pass B: weights + PV ----------------
    dma(Kbh, kb0);
    dma(Vtbh, vb0);
    __syncthreads();

    f32x4 oacc[8];
#pragma unroll
    for (int f = 0; f < 8; ++f) oacc[f] = zero;

    {
        char* kcur = kb0; char* knxt = kb1;
        char* vcur = vb0; char* vnxt = vb1;
        for (int t = 0; t < NT; ++t) {
            const int kc = t * BN;
            if (t + 1 < NT) {
                dma(Kbh  + (size_t)(t + 1) * 16384, knxt);
                dma(Vtbh + (size_t)(t + 1) * 16384, vnxt);
            }

            uint2 mw[4];
#pragma unroll
            for (int r = 0; r < 4; ++r)
                mw[r] = *reinterpret_cast<const uint2*>(mbase[r] + 2 * t);

            f32x4 s[4] = {zero, zero, zero, zero};
#pragma unroll
            for (int dsv = 0; dsv < 8; ++dsv) {
                const int koff = (dsv * 32 + lg * 8) ^ ((lr & 7) << 4);
#pragma unroll
                for (int tt = 0; tt < 4; ++tt) {
                    const s16x4 bb = *reinterpret_cast<const s16x4*>(
                        kcur + (16 * tt + lr) * 256 + koff);
                    s[tt] = MFMA16(qf[dsv], bb, s[tt]);
                }
            }

#pragma unroll
            for (int tt = 0; tt < 4; ++tt) {
#pragma unroll
                for (int r = 0; r < 4; ++r) {
                    const unsigned wsel = (tt < 2) ? mw[r].x : mw[r].y;
                    const unsigned bit = (wsel >> ((tt & 1) * 16 + lr)) & 1u;
                    const float e = bit ? __builtin_amdgcn_exp2f(s[tt][r] + li[r]) : 0.f;
                    Wg[(size_t)(qrow + r) * Sn + kc + 16 * tt + lr] = e;
                    wl[(qrow + r) * 70 + 16 * tt + lr] = f2bu(e);
                }
            }
            // no barrier: each wave writes/reads only its own 16 wl rows

#pragma unroll
            for (int kk = 0; kk < 4; ++kk) {
                const s16x4 aw = *reinterpret_cast<const s16x4*>(
                    reinterpret_cast<const char*>(wl) + (16 * wv + lr) * 140 + kk * 32 + lg * 8);
#pragma unroll
                for (int f = 0; f < 8; ++f) {
                    const s16x4 bv = *reinterpret_cast<const s16x4*>(
                        vcur + (16 * f + lr) * 128 + ((kk * 32 + lg * 8) ^ ((lr & 7) << 4)));
                    oacc[f] = MFMA16(aw, bv, oacc[f]);
                }
            }

            __syncthreads();
            char* tmp = kcur; kcur = knxt; knxt = tmp;
            tmp = vcur; vcur = vnxt; vnxt = tmp;
        }
    }

    // ---------------- epilogue: O ----------------
#pragma unroll
    for (int f = 0; f < 8; ++f)
#pragma unroll
        for (int r = 0; r < 4; ++r)
            Og[(size_t)(qrow + r) * Dn + 16 * f + lr] = oacc[f][r];
}

// ================= fallback (round-3 kernel, verified 1006 us) =================

constexpr int FQSTR = 136;
constexpr int FVSTR = 68;

__device__ __forceinline__ void fbk_issue(const float* __restrict__ g, int sc, int sr,
                                          float4* v) {
#pragma unroll
    for (int it = 0; it < 4; ++it) {
        const float4* gp = reinterpret_cast<const float4*>(
            g + (size_t)(sr + 16 * it) * Dn + sc * 8);
        v[2 * it]     = gp[0];
        v[2 * it + 1] = gp[1];
    }
}
__device__ __forceinline__ void fbk_write(unsigned short* lds, int sc, int sr,
                                          const float4* v) {
#pragma unroll
    for (int it = 0; it < 4; ++it) {
        const int r = sr + 16 * it;
        uint4 u;
        u.x = pk2(v[2 * it].x,     v[2 * it].y);
        u.y = pk2(v[2 * it].z,     v[2 * it].w);
        u.z = pk2(v[2 * it + 1].x, v[2 * it + 1].y);
        u.w = pk2(v[2 * it + 1].z, v[2 * it + 1].w);
        *reinterpret_cast<uint4*>(reinterpret_cast<char*>(lds) + r * (FQSTR * 2) + sc * 16) = u;
    }
}
__device__ __forceinline__ void fbv_issue(const float* __restrict__ g, int tc, int kp,
                                          float4* v) {
#pragma unroll
    for (int it = 0; it < 4; ++it) {
        const int kr = 2 * (kp + 8 * it);
        v[2 * it]     = *reinterpret_cast<const float4*>(g + (size_t)kr * Dn + 4 * tc);
        v[2 * it + 1] = *reinterpret_cast<const float4*>(g + (size_t)(kr + 1) * Dn + 4 * tc);
    }
}
__device__ __forceinline__ void fbv_write(unsigned short* vt, int tc, int kp,
                                          const float4* v) {
#pragma unroll
    for (int it = 0; it < 4; ++it) {
        const int kr = 2 * (kp + 8 * it);
        const float a4[4] = {v[2 * it].x, v[2 * it].y, v[2 * it].z, v[2 * it].w};
        const float b4[4] = {v[2 * it + 1].x, v[2 * it + 1].y, v[2 * it + 1].z, v[2 * it + 1].w};
#pragma unroll
        for (int j = 0; j < 4; ++j) {
            const int d = 4 * tc + j;
            *reinterpret_cast<unsigned*>(reinterpret_cast<char*>(vt) + d * (FVSTR * 2) + kr * 2)
                = pk2(a4[j], b4[j]);
        }
    }
}

__global__ __launch_bounds__(256)
void attn_fb(const float* __restrict__ Q, const float* __restrict__ K,
             const float* __restrict__ V, const int* __restrict__ M,
             float* __restrict__ out) {
    __shared__ __align__(16) unsigned short fsm[8704 * 2 + 64 * FVSTR];
    unsigned short* bufA = fsm;
    unsigned short* bufB = fsm + 8704;
    unsigned short* wl2  = fsm + 17408;

    const int tid  = threadIdx.x;
    const int lane = tid & 63;
    const int wv   = tid >> 6;
    const int lr   = lane & 15;
    const int lg   = lane >> 4;

    const int bh    = blockIdx.y;
    const int b     = bh >> 4;
    const int qbase = blockIdx.x * 64;

    const float* Qg = Q + ((size_t)bh * Sn + qbase) * Dn;
    const float* Kg = K + (size_t)bh * Sn * Dn;
    const float* Vg = V + (size_t)bh * Sn * Dn;
    const int*   Mg = M + ((size_t)b * Sn + qbase) * Sn;
    float*       Og = out + ((size_t)bh * Sn + qbase) * Dn;
    float*       Wg = out + OUT0 + ((size_t)bh * Sn + qbase) * Sn;

    const float scl2 = QSs;
    const int qrow = 16 * wv + 4 * lg;

    const int sc = tid & 15, sr = tid >> 4;
    const int tc = tid & 31, kp = tid >> 5;

    const int* mrow[4];
#pragma unroll
    for (int r = 0; r < 4; ++r) mrow[r] = Mg + (size_t)(qrow + r) * Sn + lr;

    {
        float4 qv[8], kv[8];
        fbk_issue(Qg, sc, sr, qv);
        fbk_issue(Kg, sc, sr, kv);
        fbk_write(bufB, sc, sr, qv);
        fbk_write(bufA, sc, sr, kv);
    }
    __syncthreads();
    s16x4 qf[8];
#pragma unroll
    for (int dsv = 0; dsv < 8; ++dsv)
        qf[dsv] = *reinterpret_cast<const s16x4*>(
            reinterpret_cast<const char*>(bufB) + (16 * wv + lr) * (FQSTR * 2) + dsv * 32 + lg * 8);
    __syncthreads();

    const f32x4 zero = {0.f, 0.f, 0.f, 0.f};

    auto qk_tile = [&](const unsigned short* kb) {
        struct { f32x4 t[4]; } s;
#pragma unroll
        for (int t = 0; t < 4; ++t) s.t[t] = zero;
#pragma unroll
        for (int dsv = 0; dsv < 8; ++dsv) {
            const int koff = dsv * 32 + lg * 8;
#pragma unroll
            for (int t = 0; t < 4; ++t) {
                const s16x4 bb = *reinterpret_cast<const s16x4*>(
                    reinterpret_cast<const char*>(kb) + (16 * t + lr) * (FQSTR * 2) + koff);
                s.t[t] = MFMA16(qf[dsv], bb, s.t[t]);
            }
        }
        return s;
    };

    float rs[4] = {0.f, 0.f, 0.f, 0.f};
    for (int t = 0; t < NT; ++t) {
        unsigned short* cur = (t & 1) ? bufB : bufA;
        unsigned short* nxt = (t & 1) ? bufA : bufB;
        float4 kv[8];
        const bool pre = (t + 1 < NT);
        if (pre) fbk_issue(Kg + (size_t)(t + 1) * BN * Dn, sc, sr, kv);

        int mv[16];
        const int kc = t * BN;
#pragma unroll
        for (int tt = 0; tt < 4; ++tt)
#pragma unroll
            for (int r = 0; r < 4; ++r) mv[4 * tt + r] = mrow[r][kc + 16 * tt];

        auto s = qk_tile(cur);
#pragma unroll
        for (int tt = 0; tt < 4; ++tt)
#pragma unroll
            for (int r = 0; r < 4; ++r)
                rs[r] += mv[4 * tt + r] ? __builtin_amdgcn_exp2f(s.t[tt][r] * scl2) : 0.f;

        if (pre) fbk_write(nxt, sc, sr, kv);
        __syncthreads();
    }

    float inv[4];
#pragma unroll
    for (int r = 0; r < 4; ++r) {
        float v = rs[r];
        v += __shfl_xor(v, 1);
        v += __shfl_xor(v, 2);
        v += __shfl_xor(v, 4);
        v += __shfl_xor(v, 8);
        inv[r] = 1.0f / v;
    }

    {
        float4 kv0[8], vv0[8];
        fbk_issue(Kg, sc, sr, kv0);
        fbv_issue(Vg, tc, kp, vv0);
        fbk_write(bufA, sc, sr, kv0);
        fbv_write(bufB, tc, kp, vv0);
    }
    __syncthreads();

    f32x4 oacc[8];
#pragma unroll
    for (int f = 0; f < 8; ++f) oacc[f] = zero;

    for (int t = 0; t < NT; ++t) {
        float4 kv[8], vv[8];
        const bool pre = (t + 1 < NT);
        if (pre) {
            fbk_issue(Kg + (size_t)(t + 1) * BN * Dn, sc, sr, kv);
            fbv_issue(Vg + (size_t)(t + 1) * BN * Dn, tc, kp, vv);
        }

        int mv[16];
        const int kc = t * BN;
#pragma unroll
        for (int tt = 0; tt < 4; ++tt)
#pragma unroll
            for (int r = 0; r < 4; ++r) mv[4 * tt + r] = mrow[r][kc + 16 * tt];

        auto s = qk_tile(bufA);

#pragma unroll
        for (int tt = 0; tt < 4; ++tt) {
#pragma unroll
            for (int r = 0; r < 4; ++r) {
                const float e = mv[4 * tt + r] ? __builtin_amdgcn_exp2f(s.t[tt][r] * scl2) : 0.f;
                const float w = e * inv[r];
                Wg[(size_t)(qrow + r) * Sn + kc + 16 * tt + lr] = w;
                reinterpret_cast<unsigned short*>(
                    reinterpret_cast<char*>(wl2) + (qrow + r) * (FVSTR * 2))[16 * tt + lr] = f2bu(w);
            }
        }

#pragma unroll
        for (int kk = 0; kk < 4; ++kk) {
            const int koff = kk * 32 + lg * 8;
            const s16x4 aw = *reinterpret_cast<const s16x4*>(
                reinterpret_cast<const char*>(wl2) + (16 * wv + lr) * (FVSTR * 2) + koff);
#pragma unroll
            for (int f = 0; f < 8; ++f) {
                const s16x4 bv = *reinterpret_cast<const s16x4*>(
                    reinterpret_cast<const char*>(bufB) + (16 * f + lr) * (FVSTR * 2) + koff);
                oacc[f] = MFMA16(aw, bv, oacc[f]);
            }
        }
        __syncthreads();
        if (pre) {
            fbk_write(bufA, sc, sr, kv);
            fbv_write(bufB, tc, kp, vv);
        }
        __syncthreads();
    }

#pragma unroll
    for (int f = 0; f < 8; ++f)
#pragma unroll
        for (int r = 0; r < 4; ++r)
            Og[(size_t)(qrow + r) * Dn + 16 * f + lr] = oacc[f][r];
}

} // namespace

extern "C" void kernel_launch(void* const* d_in, const int* in_sizes, int n_in,
                              void* d_out, int out_size, void* d_ws, size_t ws_size,
                              hipStream_t stream) {
    (void)in_sizes; (void)n_in; (void)out_size;
    const float* Q = (const float*)d_in[0];
    const float* K = (const float*)d_in[1];
    const float* V = (const float*)d_in[2];
    const int*   M = (const int*)d_in[3];
    float* out = (float*)d_out;

    if (ws_size >= WS_NEED) {
        char* ws = (char*)d_ws;
        cvt_rows<<<dim3(8192), dim3(256), 0, stream>>>(Q, ws + QB_OFF, QSs);
        cvt_rows<<<dim3(8192), dim3(256), 0, stream>>>(K, ws + KB_OFF, 1.0f);
        cvt_vt  <<<dim3(8192), dim3(256), 0, stream>>>(V, ws + VT_OFF);
        mask_pack<<<dim3(2048), dim3(256), 0, stream>>>(M, (unsigned*)(ws + MB_OFF));
        attn_main<<<dim3(Sn / 64, NH), dim3(THREADS), 0, stream>>>(
            ws, (const unsigned*)(ws + MB_OFF), out);
    } else {
        attn_fb<<<dim3(Sn / 64, NH), dim3(256), 0, stream>>>(Q, K, V, M, out);
    }
}